// Round 9
// baseline (915.966 us; speedup 1.0000x reference)
//
#include <hip/hip_runtime.h>

#define TOKENS 8192
#define HID 2048
#define NEXP 8
#define NT 32          // K tiles = 2048/64
#define MAXTILES 72    // sum over experts of ceil(cnt/256) <= 64+8

typedef float f32x4 __attribute__((ext_vector_type(4)));
typedef short bf16x8 __attribute__((ext_vector_type(8)));

// ws layout (bytes)
#define WS_XBF     0ULL           // 8192 x 2048 bf16 (interleaved k)
#define WS_ACT     33554432ULL    // 16384 x 2048 bf16 (interleaved k)
#define WS_WCAT    100663296ULL   // 8 x 4096 x 2048 bf16  [e][n'][k-int], n' = g/u 16-col interleave
#define WS_WDT     234881024ULL   // 8 x 2048 x 2048 bf16  [e][n][k-int]
#define WS_ROWTOK  301989888ULL   // 16384 int
#define WS_ROWPROB 302055424ULL   // 16384 float
#define WS_EIDX    302120960ULL   // 8192 int2
#define WS_PROBS   302186496ULL   // 8192 float2
#define WS_META    302252032ULL   // [0..7]=counts [8..15]=fill [16..23]=offsets
                                  // [24]=ntiles [32..32+MAXTILES)=tilemap (e<<8|rt)

__device__ __forceinline__ unsigned short f2bf(float f) {
    union { float f; unsigned int u; } a; a.f = f;
    unsigned int r = a.u + 0x7fffu + ((a.u >> 16) & 1u);
    return (unsigned short)(r >> 16);
}

__device__ __forceinline__ void gload16(void* ldsdst, const void* gsrc) {
    __builtin_amdgcn_global_load_lds(
        (const __attribute__((address_space(1))) void*)gsrc,
        (__attribute__((address_space(3))) void*)ldsdst, 16, 0, 0);
}

#define BAR asm volatile("s_barrier" ::: "memory")
#define VM4 asm volatile("s_waitcnt vmcnt(4)" ::: "memory")
#define VM0 asm volatile("s_waitcnt vmcnt(0)" ::: "memory")

// ---------------------------------------------------------------- router
__global__ __launch_bounds__(256) void router_kernel(
    const float* __restrict__ x, const float* __restrict__ Wr,
    unsigned short* __restrict__ xbf, int2* __restrict__ eidx,
    float2* __restrict__ probs, int* __restrict__ meta) {
    __shared__ float wrt[NEXP * HID];   // 64 KiB, [e][i]
    int tid = threadIdx.x;
    for (int f = tid; f < HID * NEXP; f += 256) {
        int i = f >> 3, e = f & 7;
        wrt[e * HID + i] = Wr[f];
    }
    __syncthreads();
    int w = tid >> 6, l = tid & 63;
    int tok = blockIdx.x * 4 + w;
    const float4* xr = (const float4*)(x + (size_t)tok * HID);
    float acc[NEXP];
#pragma unroll
    for (int e = 0; e < NEXP; ++e) acc[e] = 0.f;
    unsigned long long* xbr = (unsigned long long*)(xbf + (size_t)tok * HID);
#pragma unroll
    for (int it = 0; it < 8; ++it) {
        float4 v = xr[it * 64 + l];
        int k0 = (it * 64 + l) * 4;
#pragma unroll
        for (int e = 0; e < NEXP; ++e) {
            float4 wv = *(const float4*)&wrt[e * HID + k0];
            acc[e] += v.x * wv.x + v.y * wv.y + v.z * wv.z + v.w * wv.w;
        }
        unsigned long long pk = (unsigned long long)f2bf(v.x)
                              | ((unsigned long long)f2bf(v.y) << 16)
                              | ((unsigned long long)f2bf(v.z) << 32)
                              | ((unsigned long long)f2bf(v.w) << 48);
        int qi = ((k0 >> 5) << 3) + (((k0 >> 2) & 3) << 1) + ((k0 >> 4) & 1);
        xbr[qi] = pk;
    }
#pragma unroll
    for (int e = 0; e < NEXP; ++e) {
#pragma unroll
        for (int d = 1; d < 64; d <<= 1) acc[e] += __shfl_xor(acc[e], d, 64);
    }
    if (l == 0) {
        int e0 = 0; float v0 = acc[0];
#pragma unroll
        for (int e = 1; e < NEXP; ++e) if (acc[e] > v0) { v0 = acc[e]; e0 = e; }
        int e1 = -1; float v1 = 0.f;
#pragma unroll
        for (int e = 0; e < NEXP; ++e)
            if (e != e0 && (e1 < 0 || acc[e] > v1)) { v1 = acc[e]; e1 = e; }
        float a = __expf(v1 - v0);
        float inv = 1.f / (1.f + a);
        int2 ei; ei.x = e0; ei.y = e1;
        float2 pp; pp.x = inv; pp.y = a * inv;
        eidx[tok] = ei;
        probs[tok] = pp;
        atomicAdd(&meta[e0], 1);
        atomicAdd(&meta[e1], 1);
    }
}

// ---------------------------------------------------------------- weight convert+transpose
__global__ __launch_bounds__(256) void convert_kernel(
    const float* __restrict__ Wg, const float* __restrict__ Wu,
    const float* __restrict__ Wd, unsigned short* __restrict__ wcat,
    unsigned short* __restrict__ wdt) {
    int mz = blockIdx.z;
    int mat = mz >> 3, e = mz & 7;
    const float* W = (mat == 0 ? Wg : (mat == 1 ? Wu : Wd)) + (size_t)e * HID * HID;
    int kb = blockIdx.y * 64, nb = blockIdx.x * 64;
    __shared__ unsigned short t[64][68];
    int tid = threadIdx.x;
    int kr = tid >> 4;
    int nc = (tid & 15) * 4;
#pragma unroll
    for (int ki = 0; ki < 4; ++ki) {
        int k = kr + ki * 16;
        float4 v = *(const float4*)&W[(size_t)(kb + k) * HID + nb + nc];
        t[nc + 0][k] = f2bf(v.x);
        t[nc + 1][k] = f2bf(v.y);
        t[nc + 2][k] = f2bf(v.z);
        t[nc + 3][k] = f2bf(v.w);
    }
    __syncthreads();
    int n = tid >> 2;        // 0..63
    int seg = tid & 3;       // 4 qwords (32 B) each
    int gn = nb + n;
    unsigned short* orow;
    if (mat < 2)
        orow = wcat + ((size_t)e * 4096 + (gn >> 4) * 32 + mat * 16 + (gn & 15)) * HID;
    else
        orow = wdt + ((size_t)e * HID + gn) * HID;
    unsigned long long pk[4];
#pragma unroll
    for (int j = 0; j < 4; ++j) {
        int qi = seg * 4 + j;
        int klocal = ((qi >> 3) << 5) + (((qi >> 1) & 3) << 2) + ((qi & 1) << 4);
        pk[j] = *(const unsigned long long*)&t[n][klocal];
    }
    unsigned long long* dst = (unsigned long long*)&orow[kb + seg * 16];
    dst[0] = pk[0]; dst[1] = pk[1]; dst[2] = pk[2]; dst[3] = pk[3];
}

// ---------------------------------------------------------------- scan + tile map
__global__ void scan_kernel(int* __restrict__ meta) {
    if (threadIdx.x == 0) {
        int s = 0, tiles = 0;
#pragma unroll
        for (int e = 0; e < NEXP; ++e) {
            meta[16 + e] = s;
            int c = meta[e];
            int nt = (c + 255) >> 8;
            for (int i = 0; i < nt && tiles < MAXTILES; ++i)
                meta[32 + tiles++] = (e << 8) | i;
            s += c;
        }
        meta[24] = tiles;
    }
}

// ---------------------------------------------------------------- build expanded rows
__global__ __launch_bounds__(256) void build_kernel(
    const int2* __restrict__ eidx, const float2* __restrict__ probs,
    int* __restrict__ meta, int* __restrict__ row_token, float* __restrict__ row_prob) {
    int t = blockIdx.x * 256 + threadIdx.x;
    if (t >= TOKENS) return;
    int2 e = eidx[t];
    float2 p = probs[t];
    int s0 = meta[16 + e.x] + atomicAdd(&meta[8 + e.x], 1);
    row_token[s0] = t; row_prob[s0] = p.x;
    int s1 = meta[16 + e.y] + atomicAdd(&meta[8 + e.y], 1);
    row_token[s1] = t; row_prob[s1] = p.y;
}

// ---------------------------------------------------------------- pipelined GEMM macros
// LDS map: A half (d,kh) at d*32768 + kh*16384 ; B half at +65536. 128 KiB.
// Swizzle: physical 16B unit u of LDS row r holds logical unit u ^ ((r>>1)&3)
// (write: pre-swizzled global source; read: same XOR — conflict-free, PMC=0).
// Schedule: round-5 2-barrier/K-tile cross-phase pipelined loop (equal-best).
#define STA(dn, kh, tt) { char* _d = lds + (dn)*32768 + (kh)*16384 + tid*16; \
    gload16(_d,        a0 + (tt)*64 + (kh)*32); \
    gload16(_d + 8192, a1 + (tt)*64 + (kh)*32); }
#define STB(dn, kh, tt) { char* _d = lds + (dn)*32768 + 65536 + (kh)*16384 + tid*16; \
    gload16(_d,        b0 + (tt)*64 + (kh)*32); \
    gload16(_d + 8192, b1 + (tt)*64 + (kh)*32); }
#define LDA_TO(dst, d, kh) { const char* _b = lds + (d)*32768 + (kh)*16384 + afo; \
    dst[0] = *(const bf16x8*)(_b);        dst[1] = *(const bf16x8*)(_b + 1024); \
    dst[2] = *(const bf16x8*)(_b + 2048); dst[3] = *(const bf16x8*)(_b + 3072); \
    dst[4] = *(const bf16x8*)(_b + 4096); dst[5] = *(const bf16x8*)(_b + 5120); \
    dst[6] = *(const bf16x8*)(_b + 6144); dst[7] = *(const bf16x8*)(_b + 7168); }
#define LDB(d, kh, nn) (*(const bf16x8*)(lds + (d)*32768 + (kh)*16384 + bfo + (nn)*1024))
#define MM(A, B0, B1, n0, n1) do { \
    __builtin_amdgcn_s_setprio(1); \
    _Pragma("unroll") \
    for (int m = 0; m < 8; ++m) { \
        acc[m][n0] = __builtin_amdgcn_mfma_f32_16x16x32_bf16(A[m], B0, acc[m][n0], 0, 0, 0); \
        acc[m][n1] = __builtin_amdgcn_mfma_f32_16x16x32_bf16(A[m], B1, acc[m][n1], 0, 0, 0); \
    } \
    __builtin_amdgcn_s_setprio(0); \
} while (0)

#define GEMM_MAIN_LOOP \
    f32x4 acc[8][4]; \
    { f32x4 z = {0.f,0.f,0.f,0.f}; \
      _Pragma("unroll") for (int m=0;m<8;++m) \
      _Pragma("unroll") for (int n=0;n<4;++n) acc[m][n]=z; } \
    bf16x8 af[8], af2[8], bq0, bq1, bq2, bq3; \
    STA(0, 0, 0); STB(0, 0, 0); STA(0, 1, 0); STB(0, 1, 0); \
    VM4; BAR; \
    LDA_TO(af, 0, 0); bq0 = LDB(0, 0, 0); bq1 = LDB(0, 0, 1); \
    for (int t = 0; t < NT - 1; ++t) { \
        const int d = t & 1, dn = d ^ 1, tn = t + 1; \
        bq2 = LDB(d, 0, 2); bq3 = LDB(d, 0, 3); \
        STA(dn, 0, tn); \
        MM(af, bq0, bq1, 0, 1); \
        STB(dn, 0, tn); \
        VM4; BAR; \
        LDA_TO(af2, d, 1); bq0 = LDB(d, 1, 0); bq1 = LDB(d, 1, 1); \
        MM(af, bq2, bq3, 2, 3); \
        bq2 = LDB(d, 1, 2); bq3 = LDB(d, 1, 3); \
        STA(dn, 1, tn); \
        MM(af2, bq0, bq1, 0, 1); \
        STB(dn, 1, tn); \
        VM4; BAR; \
        LDA_TO(af, dn, 0); bq0 = LDB(dn, 0, 0); bq1 = LDB(dn, 0, 1); \
        MM(af2, bq2, bq3, 2, 3); \
    } \
    { const int d = (NT - 1) & 1; \
        bq2 = LDB(d, 0, 2); bq3 = LDB(d, 0, 3); \
        MM(af, bq0, bq1, 0, 1); \
        VM0; BAR; \
        LDA_TO(af2, d, 1); bq0 = LDB(d, 1, 0); bq1 = LDB(d, 1, 1); \
        MM(af, bq2, bq3, 2, 3); \
        bq2 = LDB(d, 1, 2); bq3 = LDB(d, 1, 3); \
        MM(af2, bq0, bq1, 0, 1); \
        MM(af2, bq2, bq3, 2, 3); \
    }

// ---------------------------------------------------------------- GEMM1: act = swiglu(x @ wcat)
__global__ __launch_bounds__(512) void gemm1_kernel(
    const unsigned short* __restrict__ xbf, const unsigned short* __restrict__ wcat,
    const int* __restrict__ row_token, const int* __restrict__ meta,
    unsigned short* __restrict__ act) {
    int ty = blockIdx.y;
    if (ty >= meta[24]) return;
    int mp = meta[32 + ty];
    int e = mp >> 8, rt = mp & 255;
    int cnt = meta[e];
    int off = meta[16 + e];
    int ct = blockIdx.x;                 // 0..15 over N'=4096
    __shared__ __align__(16) char lds[131072];
    int tid = threadIdx.x, w = tid >> 6, l = tid & 63;
    int wr = w >> 2, wc = w & 3;
    int r16 = l & 15, g = l >> 4;

    // staging sources (pre-swizzled unit within row)
    int srow = tid >> 2;
    int sxu = (tid & 3) ^ ((tid >> 3) & 3);
    int rr0 = rt * 256 + srow;       if (rr0 >= cnt) rr0 = cnt - 1;
    int rr1 = rt * 256 + srow + 128; if (rr1 >= cnt) rr1 = cnt - 1;
    const unsigned short* a0 = xbf + (size_t)row_token[off + rr0] * HID + sxu * 8;
    const unsigned short* a1 = xbf + (size_t)row_token[off + rr1] * HID + sxu * 8;
    const unsigned short* b0 = wcat + ((size_t)(e * 4096 + ct * 256 + srow)) * HID + sxu * 8;
    const unsigned short* b1 = b0 + (size_t)128 * HID;

    int sw = (r16 >> 1) & 3;
    int afo = (wr * 128 + r16) * 64 + (g ^ sw) * 16;
    int bfo = 65536 + (wc * 64 + r16) * 64 + (g ^ sw) * 16;

    GEMM_MAIN_LOOP

    // epilogue: swiglu on (g,u) frag pairs, store act interleaved-k
    int pb = (ct * 4 + wc) * 32 + (r16 >> 2) * 8 + (r16 & 3);  // + p*4
#pragma unroll
    for (int m = 0; m < 8; ++m) {
        int rbase = wr * 128 + m * 16 + (l >> 4) * 4;
#pragma unroll
        for (int q = 0; q < 4; ++q) {
            int r = rt * 256 + rbase + q;
            if (r < cnt) {
                unsigned short* arow = act + (size_t)(off + r) * HID;
#pragma unroll
                for (int p = 0; p < 2; ++p) {
                    float gg = acc[m][2 * p][q];
                    float uu = acc[m][2 * p + 1][q];
                    float s = gg / (1.f + __expf(-gg));
                    s = fminf(fmaxf(s, -7.f), 7.f);
                    arow[pb + p * 4] = f2bf(s * uu);
                }
            }
        }
    }
}

// ---------------------------------------------------------------- GEMM2: out += p * (act @ wdt)
__global__ __launch_bounds__(512) void gemm2_kernel(
    const unsigned short* __restrict__ act, const unsigned short* __restrict__ wdt,
    const int* __restrict__ row_token, const float* __restrict__ row_prob,
    const int* __restrict__ meta, float* __restrict__ out) {
    int ty = blockIdx.y;
    if (ty >= meta[24]) return;
    int mp = meta[32 + ty];
    int e = mp >> 8, rt = mp & 255;
    int cnt = meta[e];
    int off = meta[16 + e];
    int ct = blockIdx.x;                 // 0..7 over N=2048
    __shared__ __align__(16) char lds[131072];
    int tid = threadIdx.x, w = tid >> 6, l = tid & 63;
    int wr = w >> 2, wc = w & 3;
    int r16 = l & 15, g = l >> 4;

    int srow = tid >> 2;
    int sxu = (tid & 3) ^ ((tid >> 3) & 3);
    int rr0 = rt * 256 + srow;       if (rr0 >= cnt) rr0 = cnt - 1;
    int rr1 = rt * 256 + srow + 128; if (rr1 >= cnt) rr1 = cnt - 1;
    const unsigned short* a0 = act + (size_t)(off + rr0) * HID + sxu * 8;
    const unsigned short* a1 = act + (size_t)(off + rr1) * HID + sxu * 8;
    const unsigned short* b0 = wdt + ((size_t)(e * HID + ct * 256 + srow)) * HID + sxu * 8;
    const unsigned short* b1 = b0 + (size_t)128 * HID;

    int sw = (r16 >> 1) & 3;
    int afo = (wr * 128 + r16) * 64 + (g ^ sw) * 16;
    int bfo = 65536 + (wc * 64 + r16) * 64 + (g ^ sw) * 16;

    GEMM_MAIN_LOOP

    int colb = ct * 256 + wc * 64;
#pragma unroll
    for (int m = 0; m < 8; ++m) {
        int rbase = wr * 128 + m * 16 + (l >> 4) * 4;
#pragma unroll
        for (int q = 0; q < 4; ++q) {
            int r = rt * 256 + rbase + q;
            if (r < cnt) {
                int slot = off + r;
                int tok = row_token[slot];
                float pr = row_prob[slot];
                float* orow = out + (size_t)tok * HID + colb;
#pragma unroll
                for (int nn = 0; nn < 4; ++nn)
                    unsafeAtomicAdd(&orow[nn * 16 + r16], acc[m][nn][q] * pr);
            }
        }
    }
}

// ---------------------------------------------------------------- launch
extern "C" void kernel_launch(void* const* d_in, const int* in_sizes, int n_in,
                              void* d_out, int out_size, void* d_ws, size_t ws_size,
                              hipStream_t stream) {
    const float* x  = (const float*)d_in[0];
    const float* Wr = (const float*)d_in[1];
    const float* Wg = (const float*)d_in[2];
    const float* Wu = (const float*)d_in[3];
    const float* Wd = (const float*)d_in[4];
    float* out = (float*)d_out;
    char* ws = (char*)d_ws;

    unsigned short* xbf  = (unsigned short*)(ws + WS_XBF);
    unsigned short* act  = (unsigned short*)(ws + WS_ACT);
    unsigned short* wcat = (unsigned short*)(ws + WS_WCAT);
    unsigned short* wdt  = (unsigned short*)(ws + WS_WDT);
    int* row_token  = (int*)(ws + WS_ROWTOK);
    float* row_prob = (float*)(ws + WS_ROWPROB);
    int2* eidx      = (int2*)(ws + WS_EIDX);
    float2* probs   = (float2*)(ws + WS_PROBS);
    int* meta       = (int*)(ws + WS_META);

    hipMemsetAsync(d_out, 0, (size_t)out_size * sizeof(float), stream);
    hipMemsetAsync(meta, 0, 64, stream);

    hipLaunchKernelGGL(convert_kernel, dim3(32, 32, 24), dim3(256), 0, stream,
                       Wg, Wu, Wd, wcat, wdt);
    hipLaunchKernelGGL(router_kernel, dim3(TOKENS / 4), dim3(256), 0, stream,
                       x, Wr, xbf, eidx, probs, meta);
    hipLaunchKernelGGL(scan_kernel, dim3(1), dim3(64), 0, stream, meta);
    hipLaunchKernelGGL(build_kernel, dim3(TOKENS / 256), dim3(256), 0, stream,
                       eidx, probs, meta, row_token, row_prob);
    hipLaunchKernelGGL(gemm1_kernel, dim3(16, MAXTILES), dim3(512), 0, stream,
                       xbf, wcat, row_token, meta, act);
    hipLaunchKernelGGL(gemm2_kernel, dim3(8, MAXTILES), dim3(512), 0, stream,
                       act, wdt, row_token, row_prob, meta, out);
}

// Round 10
// 914.516 us; speedup vs baseline: 1.0016x; 1.0016x over previous
//
#include <hip/hip_runtime.h>

#define TOKENS 8192
#define HID 2048
#define NEXP 8
#define NT 32          // K tiles = 2048/64
#define MAXTILES 72    // sum over experts of ceil(cnt/256) <= 64+8

typedef float f32x4 __attribute__((ext_vector_type(4)));
typedef short bf16x8 __attribute__((ext_vector_type(8)));

// ws layout (bytes)
#define WS_XBF     0ULL           // 8192 x 2048 bf16 (interleaved k)
#define WS_ACT     33554432ULL    // 16384 x 2048 bf16 (interleaved k)
#define WS_WCAT    100663296ULL   // 8 x 4096 x 2048 bf16  [e][n'][k-int], n' = g/u 16-col interleave
#define WS_WDT     234881024ULL   // 8 x 2048 x 2048 bf16  [e][n][k-int]
#define WS_ROWTOK  301989888ULL   // 16384 int
#define WS_ROWPROB 302055424ULL   // 16384 float
#define WS_EIDX    302120960ULL   // 8192 int2
#define WS_PROBS   302186496ULL   // 8192 float2
#define WS_META    302252032ULL   // [0..7]=counts [8..15]=fill [16..23]=offsets
                                  // [24]=ntiles [32..32+MAXTILES)=tilemap (e<<8|rt)

__device__ __forceinline__ unsigned short f2bf(float f) {
    union { float f; unsigned int u; } a; a.f = f;
    unsigned int r = a.u + 0x7fffu + ((a.u >> 16) & 1u);
    return (unsigned short)(r >> 16);
}

__device__ __forceinline__ void gload16(void* ldsdst, const void* gsrc) {
    __builtin_amdgcn_global_load_lds(
        (const __attribute__((address_space(1))) void*)gsrc,
        (__attribute__((address_space(3))) void*)ldsdst, 16, 0, 0);
}

#define BAR asm volatile("s_barrier" ::: "memory")
#define VM4 asm volatile("s_waitcnt vmcnt(4)" ::: "memory")
#define VM0 asm volatile("s_waitcnt vmcnt(0)" ::: "memory")

// ---------------------------------------------------------------- router
__global__ __launch_bounds__(256) void router_kernel(
    const float* __restrict__ x, const float* __restrict__ Wr,
    unsigned short* __restrict__ xbf, int2* __restrict__ eidx,
    float2* __restrict__ probs, int* __restrict__ meta) {
    __shared__ float wrt[NEXP * HID];   // 64 KiB, [e][i]
    int tid = threadIdx.x;
    for (int f = tid; f < HID * NEXP; f += 256) {
        int i = f >> 3, e = f & 7;
        wrt[e * HID + i] = Wr[f];
    }
    __syncthreads();
    int w = tid >> 6, l = tid & 63;
    int tok = blockIdx.x * 4 + w;
    const float4* xr = (const float4*)(x + (size_t)tok * HID);
    float acc[NEXP];
#pragma unroll
    for (int e = 0; e < NEXP; ++e) acc[e] = 0.f;
    unsigned long long* xbr = (unsigned long long*)(xbf + (size_t)tok * HID);
#pragma unroll
    for (int it = 0; it < 8; ++it) {
        float4 v = xr[it * 64 + l];
        int k0 = (it * 64 + l) * 4;
#pragma unroll
        for (int e = 0; e < NEXP; ++e) {
            float4 wv = *(const float4*)&wrt[e * HID + k0];
            acc[e] += v.x * wv.x + v.y * wv.y + v.z * wv.z + v.w * wv.w;
        }
        unsigned long long pk = (unsigned long long)f2bf(v.x)
                              | ((unsigned long long)f2bf(v.y) << 16)
                              | ((unsigned long long)f2bf(v.z) << 32)
                              | ((unsigned long long)f2bf(v.w) << 48);
        int qi = ((k0 >> 5) << 3) + (((k0 >> 2) & 3) << 1) + ((k0 >> 4) & 1);
        xbr[qi] = pk;
    }
#pragma unroll
    for (int e = 0; e < NEXP; ++e) {
#pragma unroll
        for (int d = 1; d < 64; d <<= 1) acc[e] += __shfl_xor(acc[e], d, 64);
    }
    if (l == 0) {
        int e0 = 0; float v0 = acc[0];
#pragma unroll
        for (int e = 1; e < NEXP; ++e) if (acc[e] > v0) { v0 = acc[e]; e0 = e; }
        int e1 = -1; float v1 = 0.f;
#pragma unroll
        for (int e = 0; e < NEXP; ++e)
            if (e != e0 && (e1 < 0 || acc[e] > v1)) { v1 = acc[e]; e1 = e; }
        float a = __expf(v1 - v0);
        float inv = 1.f / (1.f + a);
        int2 ei; ei.x = e0; ei.y = e1;
        float2 pp; pp.x = inv; pp.y = a * inv;
        eidx[tok] = ei;
        probs[tok] = pp;
        atomicAdd(&meta[e0], 1);
        atomicAdd(&meta[e1], 1);
    }
}

// ---------------------------------------------------------------- weight convert+transpose
__global__ __launch_bounds__(256) void convert_kernel(
    const float* __restrict__ Wg, const float* __restrict__ Wu,
    const float* __restrict__ Wd, unsigned short* __restrict__ wcat,
    unsigned short* __restrict__ wdt) {
    int mz = blockIdx.z;
    int mat = mz >> 3, e = mz & 7;
    const float* W = (mat == 0 ? Wg : (mat == 1 ? Wu : Wd)) + (size_t)e * HID * HID;
    int kb = blockIdx.y * 64, nb = blockIdx.x * 64;
    __shared__ unsigned short t[64][68];
    int tid = threadIdx.x;
    int kr = tid >> 4;
    int nc = (tid & 15) * 4;
#pragma unroll
    for (int ki = 0; ki < 4; ++ki) {
        int k = kr + ki * 16;
        float4 v = *(const float4*)&W[(size_t)(kb + k) * HID + nb + nc];
        t[nc + 0][k] = f2bf(v.x);
        t[nc + 1][k] = f2bf(v.y);
        t[nc + 2][k] = f2bf(v.z);
        t[nc + 3][k] = f2bf(v.w);
    }
    __syncthreads();
    int n = tid >> 2;        // 0..63
    int seg = tid & 3;       // 4 qwords (32 B) each
    int gn = nb + n;
    unsigned short* orow;
    if (mat < 2)
        orow = wcat + ((size_t)e * 4096 + (gn >> 4) * 32 + mat * 16 + (gn & 15)) * HID;
    else
        orow = wdt + ((size_t)e * HID + gn) * HID;
    unsigned long long pk[4];
#pragma unroll
    for (int j = 0; j < 4; ++j) {
        int qi = seg * 4 + j;
        int klocal = ((qi >> 3) << 5) + (((qi >> 1) & 3) << 2) + ((qi & 1) << 4);
        pk[j] = *(const unsigned long long*)&t[n][klocal];
    }
    unsigned long long* dst = (unsigned long long*)&orow[kb + seg * 16];
    dst[0] = pk[0]; dst[1] = pk[1]; dst[2] = pk[2]; dst[3] = pk[3];
}

// ---------------------------------------------------------------- scan + tile map
__global__ void scan_kernel(int* __restrict__ meta) {
    if (threadIdx.x == 0) {
        int s = 0, tiles = 0;
#pragma unroll
        for (int e = 0; e < NEXP; ++e) {
            meta[16 + e] = s;
            int c = meta[e];
            int nt = (c + 255) >> 8;
            for (int i = 0; i < nt && tiles < MAXTILES; ++i)
                meta[32 + tiles++] = (e << 8) | i;
            s += c;
        }
        meta[24] = tiles;
    }
}

// ---------------------------------------------------------------- build expanded rows
__global__ __launch_bounds__(256) void build_kernel(
    const int2* __restrict__ eidx, const float2* __restrict__ probs,
    int* __restrict__ meta, int* __restrict__ row_token, float* __restrict__ row_prob) {
    int t = blockIdx.x * 256 + threadIdx.x;
    if (t >= TOKENS) return;
    int2 e = eidx[t];
    float2 p = probs[t];
    int s0 = meta[16 + e.x] + atomicAdd(&meta[8 + e.x], 1);
    row_token[s0] = t; row_prob[s0] = p.x;
    int s1 = meta[16 + e.y] + atomicAdd(&meta[8 + e.y], 1);
    row_token[s1] = t; row_prob[s1] = p.y;
}

// ---------------------------------------------------------------- pipelined GEMM macros
// LDS map: A half (d,kh) at d*32768 + kh*16384 ; B half at +65536. 128 KiB.
// Swizzle: physical 16B unit u of LDS row r holds logical unit u ^ ((r>>1)&3)
// (write: pre-swizzled global source; read: same XOR — conflict-free, PMC=0).
// Schedule: round-5 2-barrier/K-tile cross-phase pipelined loop (equal-best).
#define STA(dn, kh, tt) { char* _d = lds + (dn)*32768 + (kh)*16384 + tid*16; \
    gload16(_d,        a0 + (tt)*64 + (kh)*32); \
    gload16(_d + 8192, a1 + (tt)*64 + (kh)*32); }
#define STB(dn, kh, tt) { char* _d = lds + (dn)*32768 + 65536 + (kh)*16384 + tid*16; \
    gload16(_d,        b0 + (tt)*64 + (kh)*32); \
    gload16(_d + 8192, b1 + (tt)*64 + (kh)*32); }
#define LDA_TO(dst, d, kh) { const char* _b = lds + (d)*32768 + (kh)*16384 + afo; \
    dst[0] = *(const bf16x8*)(_b);        dst[1] = *(const bf16x8*)(_b + 1024); \
    dst[2] = *(const bf16x8*)(_b + 2048); dst[3] = *(const bf16x8*)(_b + 3072); \
    dst[4] = *(const bf16x8*)(_b + 4096); dst[5] = *(const bf16x8*)(_b + 5120); \
    dst[6] = *(const bf16x8*)(_b + 6144); dst[7] = *(const bf16x8*)(_b + 7168); }
#define LDB(d, kh, nn) (*(const bf16x8*)(lds + (d)*32768 + (kh)*16384 + bfo + (nn)*1024))
#define MM(A, B0, B1, n0, n1) do { \
    __builtin_amdgcn_s_setprio(1); \
    _Pragma("unroll") \
    for (int m = 0; m < 8; ++m) { \
        acc[m][n0] = __builtin_amdgcn_mfma_f32_16x16x32_bf16(A[m], B0, acc[m][n0], 0, 0, 0); \
        acc[m][n1] = __builtin_amdgcn_mfma_f32_16x16x32_bf16(A[m], B1, acc[m][n1], 0, 0, 0); \
    } \
    __builtin_amdgcn_s_setprio(0); \
} while (0)

#define GEMM_MAIN_LOOP \
    f32x4 acc[8][4]; \
    { f32x4 z = {0.f,0.f,0.f,0.f}; \
      _Pragma("unroll") for (int m=0;m<8;++m) \
      _Pragma("unroll") for (int n=0;n<4;++n) acc[m][n]=z; } \
    bf16x8 af[8], af2[8], bq0, bq1, bq2, bq3; \
    STA(0, 0, 0); STB(0, 0, 0); STA(0, 1, 0); STB(0, 1, 0); \
    VM4; BAR; \
    LDA_TO(af, 0, 0); bq0 = LDB(0, 0, 0); bq1 = LDB(0, 0, 1); \
    for (int t = 0; t < NT - 1; ++t) { \
        const int d = t & 1, dn = d ^ 1, tn = t + 1; \
        bq2 = LDB(d, 0, 2); bq3 = LDB(d, 0, 3); \
        STA(dn, 0, tn); \
        MM(af, bq0, bq1, 0, 1); \
        STB(dn, 0, tn); \
        VM4; BAR; \
        LDA_TO(af2, d, 1); bq0 = LDB(d, 1, 0); bq1 = LDB(d, 1, 1); \
        MM(af, bq2, bq3, 2, 3); \
        bq2 = LDB(d, 1, 2); bq3 = LDB(d, 1, 3); \
        STA(dn, 1, tn); \
        MM(af2, bq0, bq1, 0, 1); \
        STB(dn, 1, tn); \
        VM4; BAR; \
        LDA_TO(af, dn, 0); bq0 = LDB(dn, 0, 0); bq1 = LDB(dn, 0, 1); \
        MM(af2, bq2, bq3, 2, 3); \
    } \
    { const int d = (NT - 1) & 1; \
        bq2 = LDB(d, 0, 2); bq3 = LDB(d, 0, 3); \
        MM(af, bq0, bq1, 0, 1); \
        VM0; BAR; \
        LDA_TO(af2, d, 1); bq0 = LDB(d, 1, 0); bq1 = LDB(d, 1, 1); \
        MM(af, bq2, bq3, 2, 3); \
        bq2 = LDB(d, 1, 2); bq3 = LDB(d, 1, 3); \
        MM(af2, bq0, bq1, 0, 1); \
        MM(af2, bq2, bq3, 2, 3); \
    }

// ---------------------------------------------------------------- GEMM1: act = swiglu(x @ wcat)
// 1D grid, 1152 blocks. XCD-chunk swizzle: chunk of 144 consecutive work-ids
// per XCD, ty-major within chunk so same-expert tiles (sharing the same 1 MB
// weight slice) are consecutive on the same XCD's L2.
__global__ __launch_bounds__(512, 2) void gemm1_kernel(
    const unsigned short* __restrict__ xbf, const unsigned short* __restrict__ wcat,
    const int* __restrict__ row_token, const int* __restrict__ meta,
    unsigned short* __restrict__ act) {
    int id = blockIdx.x;
    int sw = (id & 7) * 144 + (id >> 3);   // bijective: 1152 = 8 * 144
    int ty = sw % MAXTILES;
    int ct = sw / MAXTILES;                 // 0..15 over N'=4096
    if (ty >= meta[24]) return;
    int mp = meta[32 + ty];
    int e = mp >> 8, rt = mp & 255;
    int cnt = meta[e];
    int off = meta[16 + e];
    __shared__ __align__(16) char lds[131072];
    int tid = threadIdx.x, w = tid >> 6, l = tid & 63;
    int wr = w >> 2, wc = w & 3;
    int r16 = l & 15, g = l >> 4;

    // staging sources (pre-swizzled unit within row)
    int srow = tid >> 2;
    int sxu = (tid & 3) ^ ((tid >> 3) & 3);
    int rr0 = rt * 256 + srow;       if (rr0 >= cnt) rr0 = cnt - 1;
    int rr1 = rt * 256 + srow + 128; if (rr1 >= cnt) rr1 = cnt - 1;
    const unsigned short* a0 = xbf + (size_t)row_token[off + rr0] * HID + sxu * 8;
    const unsigned short* a1 = xbf + (size_t)row_token[off + rr1] * HID + sxu * 8;
    const unsigned short* b0 = wcat + ((size_t)(e * 4096 + ct * 256 + srow)) * HID + sxu * 8;
    const unsigned short* b1 = b0 + (size_t)128 * HID;

    int swz = (r16 >> 1) & 3;
    int afo = (wr * 128 + r16) * 64 + (g ^ swz) * 16;
    int bfo = 65536 + (wc * 64 + r16) * 64 + (g ^ swz) * 16;

    GEMM_MAIN_LOOP

    // epilogue: swiglu on (g,u) frag pairs, store act interleaved-k
    int pb = (ct * 4 + wc) * 32 + (r16 >> 2) * 8 + (r16 & 3);  // + p*4
#pragma unroll
    for (int m = 0; m < 8; ++m) {
        int rbase = wr * 128 + m * 16 + (l >> 4) * 4;
#pragma unroll
        for (int q = 0; q < 4; ++q) {
            int r = rt * 256 + rbase + q;
            if (r < cnt) {
                unsigned short* arow = act + (size_t)(off + r) * HID;
#pragma unroll
                for (int p = 0; p < 2; ++p) {
                    float gg = acc[m][2 * p][q];
                    float uu = acc[m][2 * p + 1][q];
                    float s = gg / (1.f + __expf(-gg));
                    s = fminf(fmaxf(s, -7.f), 7.f);
                    arow[pb + p * 4] = f2bf(s * uu);
                }
            }
        }
    }
}

// ---------------------------------------------------------------- GEMM2: out += p * (act @ wdt)
__global__ __launch_bounds__(512, 2) void gemm2_kernel(
    const unsigned short* __restrict__ act, const unsigned short* __restrict__ wdt,
    const int* __restrict__ row_token, const float* __restrict__ row_prob,
    const int* __restrict__ meta, float* __restrict__ out) {
    int id = blockIdx.x;
    int sw = (id & 7) * 72 + (id >> 3);    // bijective: 576 = 8 * 72
    int ty = sw % MAXTILES;
    int ct = sw / MAXTILES;                 // 0..7 over N=2048
    if (ty >= meta[24]) return;
    int mp = meta[32 + ty];
    int e = mp >> 8, rt = mp & 255;
    int cnt = meta[e];
    int off = meta[16 + e];
    __shared__ __align__(16) char lds[131072];
    int tid = threadIdx.x, w = tid >> 6, l = tid & 63;
    int wr = w >> 2, wc = w & 3;
    int r16 = l & 15, g = l >> 4;

    int srow = tid >> 2;
    int sxu = (tid & 3) ^ ((tid >> 3) & 3);
    int rr0 = rt * 256 + srow;       if (rr0 >= cnt) rr0 = cnt - 1;
    int rr1 = rt * 256 + srow + 128; if (rr1 >= cnt) rr1 = cnt - 1;
    const unsigned short* a0 = act + (size_t)(off + rr0) * HID + sxu * 8;
    const unsigned short* a1 = act + (size_t)(off + rr1) * HID + sxu * 8;
    const unsigned short* b0 = wdt + ((size_t)(e * HID + ct * 256 + srow)) * HID + sxu * 8;
    const unsigned short* b1 = b0 + (size_t)128 * HID;

    int swz = (r16 >> 1) & 3;
    int afo = (wr * 128 + r16) * 64 + (g ^ swz) * 16;
    int bfo = 65536 + (wc * 64 + r16) * 64 + (g ^ swz) * 16;

    GEMM_MAIN_LOOP

    int colb = ct * 256 + wc * 64;
#pragma unroll
    for (int m = 0; m < 8; ++m) {
        int rbase = wr * 128 + m * 16 + (l >> 4) * 4;
#pragma unroll
        for (int q = 0; q < 4; ++q) {
            int r = rt * 256 + rbase + q;
            if (r < cnt) {
                int slot = off + r;
                int tok = row_token[slot];
                float pr = row_prob[slot];
                float* orow = out + (size_t)tok * HID + colb;
#pragma unroll
                for (int nn = 0; nn < 4; ++nn)
                    unsafeAtomicAdd(&orow[nn * 16 + r16], acc[m][nn][q] * pr);
            }
        }
    }
}

// ---------------------------------------------------------------- launch
extern "C" void kernel_launch(void* const* d_in, const int* in_sizes, int n_in,
                              void* d_out, int out_size, void* d_ws, size_t ws_size,
                              hipStream_t stream) {
    const float* x  = (const float*)d_in[0];
    const float* Wr = (const float*)d_in[1];
    const float* Wg = (const float*)d_in[2];
    const float* Wu = (const float*)d_in[3];
    const float* Wd = (const float*)d_in[4];
    float* out = (float*)d_out;
    char* ws = (char*)d_ws;

    unsigned short* xbf  = (unsigned short*)(ws + WS_XBF);
    unsigned short* act  = (unsigned short*)(ws + WS_ACT);
    unsigned short* wcat = (unsigned short*)(ws + WS_WCAT);
    unsigned short* wdt  = (unsigned short*)(ws + WS_WDT);
    int* row_token  = (int*)(ws + WS_ROWTOK);
    float* row_prob = (float*)(ws + WS_ROWPROB);
    int2* eidx      = (int2*)(ws + WS_EIDX);
    float2* probs   = (float2*)(ws + WS_PROBS);
    int* meta       = (int*)(ws + WS_META);

    hipMemsetAsync(d_out, 0, (size_t)out_size * sizeof(float), stream);
    hipMemsetAsync(meta, 0, 64, stream);

    hipLaunchKernelGGL(convert_kernel, dim3(32, 32, 24), dim3(256), 0, stream,
                       Wg, Wu, Wd, wcat, wdt);
    hipLaunchKernelGGL(router_kernel, dim3(TOKENS / 4), dim3(256), 0, stream,
                       x, Wr, xbf, eidx, probs, meta);
    hipLaunchKernelGGL(scan_kernel, dim3(1), dim3(64), 0, stream, meta);
    hipLaunchKernelGGL(build_kernel, dim3(TOKENS / 256), dim3(256), 0, stream,
                       eidx, probs, meta, row_token, row_prob);
    hipLaunchKernelGGL(gemm1_kernel, dim3(16 * MAXTILES), dim3(512), 0, stream,
                       xbf, wcat, row_token, meta, act);
    hipLaunchKernelGGL(gemm2_kernel, dim3(8 * MAXTILES), dim3(512), 0, stream,
                       act, wdt, row_token, row_prob, meta, out);
}

// Round 11
// 779.235 us; speedup vs baseline: 1.1755x; 1.1736x over previous
//
#include <hip/hip_runtime.h>

#define TOKENS 8192
#define HID 2048
#define NEXP 8
#define NT 32          // K tiles = 2048/64
#define MAXTILES 72    // sum over experts of ceil(cnt/256) <= 64+8

typedef float f32x4 __attribute__((ext_vector_type(4)));
typedef short bf16x8 __attribute__((ext_vector_type(8)));

// ws layout (bytes)
#define WS_XBF     0ULL           // 8192 x 2048 bf16 (interleaved k)
#define WS_ACT     33554432ULL    // 16384 x 2048 bf16 (interleaved k)
#define WS_WCAT    100663296ULL   // 8 x 4096 x 2048 bf16 [e][n'][k-int]; REUSED by gemm2
                                  // as bf16 partials [16384][2048] (wcat dead after gemm1)
#define WS_WDT     234881024ULL   // 8 x 2048 x 2048 bf16  [e][n][k-int]
#define WS_ROWTOK  301989888ULL   // 16384 int
#define WS_ROWPROB 302055424ULL   // 16384 float
#define WS_EIDX    302120960ULL   // 8192 int2
#define WS_PROBS   302186496ULL   // 8192 float2
#define WS_META    302252032ULL   // [0..7]=counts [8..15]=fill [16..23]=offsets
                                  // [24]=ntiles [32..32+MAXTILES)=tilemap (e<<8|rt)
#define WS_SLOT    302253056ULL   // 8192 int2: token -> (slot0, slot1)

__device__ __forceinline__ unsigned short f2bf(float f) {
    union { float f; unsigned int u; } a; a.f = f;
    unsigned int r = a.u + 0x7fffu + ((a.u >> 16) & 1u);
    return (unsigned short)(r >> 16);
}

__device__ __forceinline__ float bf2f(unsigned int lo16) {
    union { unsigned int u; float f; } x; x.u = lo16 << 16; return x.f;
}

__device__ __forceinline__ void gload16(void* ldsdst, const void* gsrc) {
    __builtin_amdgcn_global_load_lds(
        (const __attribute__((address_space(1))) void*)gsrc,
        (__attribute__((address_space(3))) void*)ldsdst, 16, 0, 0);
}

#define BAR asm volatile("s_barrier" ::: "memory")
#define VM4 asm volatile("s_waitcnt vmcnt(4)" ::: "memory")
#define VM0 asm volatile("s_waitcnt vmcnt(0)" ::: "memory")

// ---------------------------------------------------------------- router
// 16 tokens per block (4 waves x 4 tokens) -> Wr staging amortized 4x.
__global__ __launch_bounds__(256) void router_kernel(
    const float* __restrict__ x, const float* __restrict__ Wr,
    unsigned short* __restrict__ xbf, int2* __restrict__ eidx,
    float2* __restrict__ probs, int* __restrict__ meta) {
    __shared__ float wrt[NEXP * HID];   // 64 KiB, [e][i]
    int tid = threadIdx.x;
    for (int f = tid; f < HID * NEXP; f += 256) {
        int i = f >> 3, e = f & 7;
        wrt[e * HID + i] = Wr[f];
    }
    __syncthreads();
    int w = tid >> 6, l = tid & 63;
#pragma unroll 1
    for (int ti = 0; ti < 4; ++ti) {
        int tok = blockIdx.x * 16 + w * 4 + ti;
        const float4* xr = (const float4*)(x + (size_t)tok * HID);
        float acc[NEXP];
#pragma unroll
        for (int e = 0; e < NEXP; ++e) acc[e] = 0.f;
        unsigned long long* xbr = (unsigned long long*)(xbf + (size_t)tok * HID);
#pragma unroll
        for (int it = 0; it < 8; ++it) {
            float4 v = xr[it * 64 + l];
            int k0 = (it * 64 + l) * 4;
#pragma unroll
            for (int e = 0; e < NEXP; ++e) {
                float4 wv = *(const float4*)&wrt[e * HID + k0];
                acc[e] += v.x * wv.x + v.y * wv.y + v.z * wv.z + v.w * wv.w;
            }
            unsigned long long pk = (unsigned long long)f2bf(v.x)
                                  | ((unsigned long long)f2bf(v.y) << 16)
                                  | ((unsigned long long)f2bf(v.z) << 32)
                                  | ((unsigned long long)f2bf(v.w) << 48);
            int qi = ((k0 >> 5) << 3) + (((k0 >> 2) & 3) << 1) + ((k0 >> 4) & 1);
            xbr[qi] = pk;
        }
#pragma unroll
        for (int e = 0; e < NEXP; ++e) {
#pragma unroll
            for (int d = 1; d < 64; d <<= 1) acc[e] += __shfl_xor(acc[e], d, 64);
        }
        if (l == 0) {
            int e0 = 0; float v0 = acc[0];
#pragma unroll
            for (int e = 1; e < NEXP; ++e) if (acc[e] > v0) { v0 = acc[e]; e0 = e; }
            int e1 = -1; float v1 = 0.f;
#pragma unroll
            for (int e = 0; e < NEXP; ++e)
                if (e != e0 && (e1 < 0 || acc[e] > v1)) { v1 = acc[e]; e1 = e; }
            float a = __expf(v1 - v0);
            float inv = 1.f / (1.f + a);
            int2 ei; ei.x = e0; ei.y = e1;
            float2 pp; pp.x = inv; pp.y = a * inv;
            eidx[tok] = ei;
            probs[tok] = pp;
            atomicAdd(&meta[e0], 1);
            atomicAdd(&meta[e1], 1);
        }
    }
}

// ---------------------------------------------------------------- weight convert+transpose
__global__ __launch_bounds__(256) void convert_kernel(
    const float* __restrict__ Wg, const float* __restrict__ Wu,
    const float* __restrict__ Wd, unsigned short* __restrict__ wcat,
    unsigned short* __restrict__ wdt) {
    int mz = blockIdx.z;
    int mat = mz >> 3, e = mz & 7;
    const float* W = (mat == 0 ? Wg : (mat == 1 ? Wu : Wd)) + (size_t)e * HID * HID;
    int kb = blockIdx.y * 64, nb = blockIdx.x * 64;
    __shared__ unsigned short t[64][68];
    int tid = threadIdx.x;
    int kr = tid >> 4;
    int nc = (tid & 15) * 4;
#pragma unroll
    for (int ki = 0; ki < 4; ++ki) {
        int k = kr + ki * 16;
        float4 v = *(const float4*)&W[(size_t)(kb + k) * HID + nb + nc];
        t[nc + 0][k] = f2bf(v.x);
        t[nc + 1][k] = f2bf(v.y);
        t[nc + 2][k] = f2bf(v.z);
        t[nc + 3][k] = f2bf(v.w);
    }
    __syncthreads();
    int n = tid >> 2;        // 0..63
    int seg = tid & 3;       // 4 qwords (32 B) each
    int gn = nb + n;
    unsigned short* orow;
    if (mat < 2)
        orow = wcat + ((size_t)e * 4096 + (gn >> 4) * 32 + mat * 16 + (gn & 15)) * HID;
    else
        orow = wdt + ((size_t)e * HID + gn) * HID;
    unsigned long long pk[4];
#pragma unroll
    for (int j = 0; j < 4; ++j) {
        int qi = seg * 4 + j;
        int klocal = ((qi >> 3) << 5) + (((qi >> 1) & 3) << 2) + ((qi & 1) << 4);
        pk[j] = *(const unsigned long long*)&t[n][klocal];
    }
    unsigned long long* dst = (unsigned long long*)&orow[kb + seg * 16];
    dst[0] = pk[0]; dst[1] = pk[1]; dst[2] = pk[2]; dst[3] = pk[3];
}

// ---------------------------------------------------------------- scan + tile map
__global__ void scan_kernel(int* __restrict__ meta) {
    if (threadIdx.x == 0) {
        int s = 0, tiles = 0;
#pragma unroll
        for (int e = 0; e < NEXP; ++e) {
            meta[16 + e] = s;
            int c = meta[e];
            int nt = (c + 255) >> 8;
            for (int i = 0; i < nt && tiles < MAXTILES; ++i)
                meta[32 + tiles++] = (e << 8) | i;
            s += c;
        }
        meta[24] = tiles;
    }
}

// ---------------------------------------------------------------- build expanded rows
// Two-level atomics: LDS counters per block, one global reserve per expert.
__global__ __launch_bounds__(256) void build_kernel(
    const int2* __restrict__ eidx, const float2* __restrict__ probs,
    int* __restrict__ meta, int* __restrict__ row_token, float* __restrict__ row_prob,
    int2* __restrict__ slots) {
    __shared__ int lc[NEXP], lbase[NEXP];
    int tid = threadIdx.x;
    if (tid < NEXP) lc[tid] = 0;
    __syncthreads();
    int t = blockIdx.x * 256 + tid;
    int2 e = eidx[t];
    float2 p = probs[t];
    int o0 = atomicAdd(&lc[e.x], 1);
    int o1 = atomicAdd(&lc[e.y], 1);
    __syncthreads();
    if (tid < NEXP) lbase[tid] = atomicAdd(&meta[8 + tid], lc[tid]);
    __syncthreads();
    int s0 = meta[16 + e.x] + lbase[e.x] + o0;
    int s1 = meta[16 + e.y] + lbase[e.y] + o1;
    row_token[s0] = t; row_prob[s0] = p.x;
    row_token[s1] = t; row_prob[s1] = p.y;
    int2 sl; sl.x = s0; sl.y = s1;
    slots[t] = sl;
}

// ---------------------------------------------------------------- pipelined GEMM macros
// LDS map: A half (d,kh) at d*32768 + kh*16384 ; B half at +65536. 128 KiB.
// Swizzle: physical 16B unit u of LDS row r holds logical unit u ^ ((r>>1)&3)
// (write: pre-swizzled global source; read: same XOR — conflict-free, PMC=0).
// Schedule: round-5 2-barrier/K-tile cross-phase pipelined loop (equal-best).
#define STA(dn, kh, tt) { char* _d = lds + (dn)*32768 + (kh)*16384 + tid*16; \
    gload16(_d,        a0 + (tt)*64 + (kh)*32); \
    gload16(_d + 8192, a1 + (tt)*64 + (kh)*32); }
#define STB(dn, kh, tt) { char* _d = lds + (dn)*32768 + 65536 + (kh)*16384 + tid*16; \
    gload16(_d,        b0 + (tt)*64 + (kh)*32); \
    gload16(_d + 8192, b1 + (tt)*64 + (kh)*32); }
#define LDA_TO(dst, d, kh) { const char* _b = lds + (d)*32768 + (kh)*16384 + afo; \
    dst[0] = *(const bf16x8*)(_b);        dst[1] = *(const bf16x8*)(_b + 1024); \
    dst[2] = *(const bf16x8*)(_b + 2048); dst[3] = *(const bf16x8*)(_b + 3072); \
    dst[4] = *(const bf16x8*)(_b + 4096); dst[5] = *(const bf16x8*)(_b + 5120); \
    dst[6] = *(const bf16x8*)(_b + 6144); dst[7] = *(const bf16x8*)(_b + 7168); }
#define LDB(d, kh, nn) (*(const bf16x8*)(lds + (d)*32768 + (kh)*16384 + bfo + (nn)*1024))
#define MM(A, B0, B1, n0, n1) do { \
    __builtin_amdgcn_s_setprio(1); \
    _Pragma("unroll") \
    for (int m = 0; m < 8; ++m) { \
        acc[m][n0] = __builtin_amdgcn_mfma_f32_16x16x32_bf16(A[m], B0, acc[m][n0], 0, 0, 0); \
        acc[m][n1] = __builtin_amdgcn_mfma_f32_16x16x32_bf16(A[m], B1, acc[m][n1], 0, 0, 0); \
    } \
    __builtin_amdgcn_s_setprio(0); \
} while (0)

#define GEMM_MAIN_LOOP \
    f32x4 acc[8][4]; \
    { f32x4 z = {0.f,0.f,0.f,0.f}; \
      _Pragma("unroll") for (int m=0;m<8;++m) \
      _Pragma("unroll") for (int n=0;n<4;++n) acc[m][n]=z; } \
    bf16x8 af[8], af2[8], bq0, bq1, bq2, bq3; \
    STA(0, 0, 0); STB(0, 0, 0); STA(0, 1, 0); STB(0, 1, 0); \
    VM4; BAR; \
    LDA_TO(af, 0, 0); bq0 = LDB(0, 0, 0); bq1 = LDB(0, 0, 1); \
    for (int t = 0; t < NT - 1; ++t) { \
        const int d = t & 1, dn = d ^ 1, tn = t + 1; \
        bq2 = LDB(d, 0, 2); bq3 = LDB(d, 0, 3); \
        STA(dn, 0, tn); \
        MM(af, bq0, bq1, 0, 1); \
        STB(dn, 0, tn); \
        VM4; BAR; \
        LDA_TO(af2, d, 1); bq0 = LDB(d, 1, 0); bq1 = LDB(d, 1, 1); \
        MM(af, bq2, bq3, 2, 3); \
        bq2 = LDB(d, 1, 2); bq3 = LDB(d, 1, 3); \
        STA(dn, 1, tn); \
        MM(af2, bq0, bq1, 0, 1); \
        STB(dn, 1, tn); \
        VM4; BAR; \
        LDA_TO(af, dn, 0); bq0 = LDB(dn, 0, 0); bq1 = LDB(dn, 0, 1); \
        MM(af2, bq2, bq3, 2, 3); \
    } \
    { const int d = (NT - 1) & 1; \
        bq2 = LDB(d, 0, 2); bq3 = LDB(d, 0, 3); \
        MM(af, bq0, bq1, 0, 1); \
        VM0; BAR; \
        LDA_TO(af2, d, 1); bq0 = LDB(d, 1, 0); bq1 = LDB(d, 1, 1); \
        MM(af, bq2, bq3, 2, 3); \
        bq2 = LDB(d, 1, 2); bq3 = LDB(d, 1, 3); \
        MM(af2, bq0, bq1, 0, 1); \
        MM(af2, bq2, bq3, 2, 3); \
    }

// ---------------------------------------------------------------- GEMM1: act = swiglu(x @ wcat)
__global__ __launch_bounds__(512, 2) void gemm1_kernel(
    const unsigned short* __restrict__ xbf, const unsigned short* __restrict__ wcat,
    const int* __restrict__ row_token, const int* __restrict__ meta,
    unsigned short* __restrict__ act) {
    int id = blockIdx.x;
    int sw = (id & 7) * 144 + (id >> 3);   // bijective: 1152 = 8 * 144
    int ty = sw % MAXTILES;
    int ct = sw / MAXTILES;                 // 0..15 over N'=4096
    if (ty >= meta[24]) return;
    int mp = meta[32 + ty];
    int e = mp >> 8, rt = mp & 255;
    int cnt = meta[e];
    int off = meta[16 + e];
    __shared__ __align__(16) char lds[131072];
    int tid = threadIdx.x, w = tid >> 6, l = tid & 63;
    int wr = w >> 2, wc = w & 3;
    int r16 = l & 15, g = l >> 4;

    int srow = tid >> 2;
    int sxu = (tid & 3) ^ ((tid >> 3) & 3);
    int rr0 = rt * 256 + srow;       if (rr0 >= cnt) rr0 = cnt - 1;
    int rr1 = rt * 256 + srow + 128; if (rr1 >= cnt) rr1 = cnt - 1;
    const unsigned short* a0 = xbf + (size_t)row_token[off + rr0] * HID + sxu * 8;
    const unsigned short* a1 = xbf + (size_t)row_token[off + rr1] * HID + sxu * 8;
    const unsigned short* b0 = wcat + ((size_t)(e * 4096 + ct * 256 + srow)) * HID + sxu * 8;
    const unsigned short* b1 = b0 + (size_t)128 * HID;

    int swz = (r16 >> 1) & 3;
    int afo = (wr * 128 + r16) * 64 + (g ^ swz) * 16;
    int bfo = 65536 + (wc * 64 + r16) * 64 + (g ^ swz) * 16;

    GEMM_MAIN_LOOP

    int pb = (ct * 4 + wc) * 32 + (r16 >> 2) * 8 + (r16 & 3);  // + p*4
#pragma unroll
    for (int m = 0; m < 8; ++m) {
        int rbase = wr * 128 + m * 16 + (l >> 4) * 4;
#pragma unroll
        for (int q = 0; q < 4; ++q) {
            int r = rt * 256 + rbase + q;
            if (r < cnt) {
                unsigned short* arow = act + (size_t)(off + r) * HID;
#pragma unroll
                for (int p = 0; p < 2; ++p) {
                    float gg = acc[m][2 * p][q];
                    float uu = acc[m][2 * p + 1][q];
                    float s = gg / (1.f + __expf(-gg));
                    s = fminf(fmaxf(s, -7.f), 7.f);
                    arow[pb + p * 4] = f2bf(s * uu);
                }
            }
        }
    }
}

// ---------------------------------------------------------------- GEMM2: part[slot] = act @ wdt (raw, bf16)
__global__ __launch_bounds__(512, 2) void gemm2_kernel(
    const unsigned short* __restrict__ act, const unsigned short* __restrict__ wdt,
    const int* __restrict__ meta, unsigned short* __restrict__ part) {
    int id = blockIdx.x;
    int sw = (id & 7) * 72 + (id >> 3);    // bijective: 576 = 8 * 72
    int ty = sw % MAXTILES;
    int ct = sw / MAXTILES;                 // 0..7 over N=2048
    if (ty >= meta[24]) return;
    int mp = meta[32 + ty];
    int e = mp >> 8, rt = mp & 255;
    int cnt = meta[e];
    int off = meta[16 + e];
    __shared__ __align__(16) char lds[131072];
    int tid = threadIdx.x, w = tid >> 6, l = tid & 63;
    int wr = w >> 2, wc = w & 3;
    int r16 = l & 15, g = l >> 4;

    int srow = tid >> 2;
    int sxu = (tid & 3) ^ ((tid >> 3) & 3);
    int rr0 = rt * 256 + srow;       if (rr0 >= cnt) rr0 = cnt - 1;
    int rr1 = rt * 256 + srow + 128; if (rr1 >= cnt) rr1 = cnt - 1;
    const unsigned short* a0 = act + (size_t)(off + rr0) * HID + sxu * 8;
    const unsigned short* a1 = act + (size_t)(off + rr1) * HID + sxu * 8;
    const unsigned short* b0 = wdt + ((size_t)(e * HID + ct * 256 + srow)) * HID + sxu * 8;
    const unsigned short* b1 = b0 + (size_t)128 * HID;

    int swz = (r16 >> 1) & 3;
    int afo = (wr * 128 + r16) * 64 + (g ^ swz) * 16;
    int bfo = 65536 + (wc * 64 + r16) * 64 + (g ^ swz) * 16;

    GEMM_MAIN_LOOP

    int colb = ct * 256 + wc * 64;
#pragma unroll
    for (int m = 0; m < 8; ++m) {
        int rbase = wr * 128 + m * 16 + (l >> 4) * 4;
#pragma unroll
        for (int q = 0; q < 4; ++q) {
            int r = rt * 256 + rbase + q;
            if (r < cnt) {
                unsigned short* prow = part + (size_t)(off + r) * HID + colb;
#pragma unroll
                for (int nn = 0; nn < 4; ++nn)
                    prow[nn * 16 + r16] = f2bf(acc[m][nn][q]);
            }
        }
    }
}

// ---------------------------------------------------------------- combine: out[t] = p0*P[s0] + p1*P[s1]
__global__ __launch_bounds__(256) void combine_kernel(
    const unsigned short* __restrict__ part, const int2* __restrict__ slots,
    const float2* __restrict__ probs, float* __restrict__ out) {
    int t = blockIdx.x;
    int2 s = slots[t];
    float2 p = probs[t];
    int c = threadIdx.x * 8;
    uint4 a = *(const uint4*)(part + (size_t)s.x * HID + c);
    uint4 b = *(const uint4*)(part + (size_t)s.y * HID + c);
    unsigned au[4] = {a.x, a.y, a.z, a.w};
    unsigned bu[4] = {b.x, b.y, b.z, b.w};
    float res[8];
#pragma unroll
    for (int j = 0; j < 4; ++j) {
        res[2 * j]     = p.x * bf2f(au[j] & 0xffffu) + p.y * bf2f(bu[j] & 0xffffu);
        res[2 * j + 1] = p.x * bf2f(au[j] >> 16)     + p.y * bf2f(bu[j] >> 16);
    }
    float* o = out + (size_t)t * HID + c;
    float4 o0 = {res[0], res[1], res[2], res[3]};
    float4 o1 = {res[4], res[5], res[6], res[7]};
    *(float4*)o = o0;
    *(float4*)(o + 4) = o1;
}

// ---------------------------------------------------------------- launch
extern "C" void kernel_launch(void* const* d_in, const int* in_sizes, int n_in,
                              void* d_out, int out_size, void* d_ws, size_t ws_size,
                              hipStream_t stream) {
    const float* x  = (const float*)d_in[0];
    const float* Wr = (const float*)d_in[1];
    const float* Wg = (const float*)d_in[2];
    const float* Wu = (const float*)d_in[3];
    const float* Wd = (const float*)d_in[4];
    float* out = (float*)d_out;
    char* ws = (char*)d_ws;

    unsigned short* xbf  = (unsigned short*)(ws + WS_XBF);
    unsigned short* act  = (unsigned short*)(ws + WS_ACT);
    unsigned short* wcat = (unsigned short*)(ws + WS_WCAT);
    unsigned short* part = (unsigned short*)(ws + WS_WCAT);   // reuse after gemm1
    unsigned short* wdt  = (unsigned short*)(ws + WS_WDT);
    int* row_token  = (int*)(ws + WS_ROWTOK);
    float* row_prob = (float*)(ws + WS_ROWPROB);
    int2* eidx      = (int2*)(ws + WS_EIDX);
    float2* probs   = (float2*)(ws + WS_PROBS);
    int* meta       = (int*)(ws + WS_META);
    int2* slots     = (int2*)(ws + WS_SLOT);

    hipMemsetAsync(meta, 0, 64, stream);

    hipLaunchKernelGGL(convert_kernel, dim3(32, 32, 24), dim3(256), 0, stream,
                       Wg, Wu, Wd, wcat, wdt);
    hipLaunchKernelGGL(router_kernel, dim3(TOKENS / 16), dim3(256), 0, stream,
                       x, Wr, xbf, eidx, probs, meta);
    hipLaunchKernelGGL(scan_kernel, dim3(1), dim3(64), 0, stream, meta);
    hipLaunchKernelGGL(build_kernel, dim3(TOKENS / 256), dim3(256), 0, stream,
                       eidx, probs, meta, row_token, row_prob, slots);
    hipLaunchKernelGGL(gemm1_kernel, dim3(16 * MAXTILES), dim3(512), 0, stream,
                       xbf, wcat, row_token, meta, act);
    hipLaunchKernelGGL(gemm2_kernel, dim3(8 * MAXTILES), dim3(512), 0, stream,
                       act, wdt, meta, part);
    hipLaunchKernelGGL(combine_kernel, dim3(TOKENS), dim3(256), 0, stream,
                       part, slots, probs, out);
}